// Round 5
// baseline (347.682 us; speedup 1.0000x reference)
//
#include <hip/hip_runtime.h>

#define NT    8192   // tokens
#define CIN   4096   // in_channel
#define COUT  4096   // out_channel
#define RK    16     // rank
#define ROWS  8      // tokens per block -> grid 1024 = 4 blocks/CU
#define CHUNK 256    // k per staged chunk
#define NCHUNK (CIN / CHUNK)   // 16
#define RST   36     // red row stride (floats): bank = 4*l -> 2-way = free

// async global->LDS, 16B per lane: LDS dest = wave-uniform base + lane*16,
// global src = per-lane address. Data published by the vmcnt(0) drain at the
// next __syncthreads.
__device__ __forceinline__ void gload_lds16(const float* g, float* l)
{
    __builtin_amdgcn_global_load_lds(
        (const __attribute__((address_space(1))) void*)g,
        (__attribute__((address_space(3))) void*)l, 16, 0, 0);
}

// ---------------------------------------------------------------------------
// Fused out = (x @ right^T) @ left^T + bias. One kernel, no workspace.
// grid = 1024 (8-token groups), 256 threads (4 waves).
// Phase 1 (lane = k-column): per 256-k chunk, lane l owns k = l*4..l*4+3.
//   - x: global->reg only (zero reuse), coalesced, 1-chunk-ahead prefetch.
//   - rgt: LDS double-buffered [16][256] linear via global_load_lds;
//     rv read = 64 lanes contiguous 1 KB -> conflict-free (verified: 0).
//   k is 64-way lane-split: shfl_xor(32,16) + padded-LDS reduce -> t[8][16].
// Phase 2: two half-passes of lf{0,1}[4] (32 regs) per column chunk; float2
//   stores contiguous per wave.
//
// VGPR ladder evidence: no-hint -> 204 VGPR (2 blocks/CU, Occ 11%, 142 us,
// latency-bound at HBM 18%/VALU 21%). (256,4) -> cap 64, 2.5 GB spill, 782 us.
// (256,2) -> cap 128 = the 4-waves/SIMD boundary; live set ~90 fits.
// 4 blocks/CU = grid exactly resident in one occupancy wave.
// ---------------------------------------------------------------------------
__global__ __launch_bounds__(256, 2) void fused(const float* __restrict__ x,
                                                const float* __restrict__ rgt,
                                                const float* __restrict__ lft,
                                                const float* __restrict__ bias,
                                                float* __restrict__ out)
{
    __shared__ __align__(16) float smem[8192];     // [2][4096] rgt dbuf; red aliases [0..2303]
    __shared__ __align__(16) float tl[ROWS * RK];  // t[8][16]

    const int tid = threadIdx.x;
    const int wv  = tid >> 6;
    const int l   = tid & 63;
    const int row0 = blockIdx.x * ROWS;

    // wave owns token rows {wv*2, wv*2+1}; lane owns k-cols l*4..l*4+3 per chunk
    const float* xr0 = x + (size_t)(row0 + wv * 2)     * CIN + l * 4;
    const float* xr1 = x + (size_t)(row0 + wv * 2 + 1) * CIN + l * 4;

    float4 pfx[2][2];
    float  acc[2][RK];
#pragma unroll
    for (int r = 0; r < RK; ++r) { acc[0][r] = 0.f; acc[1][r] = 0.f; }

    // ---- prologue: stage chunk 0 into buf0 (async), x chunk 0 into regs
#pragma unroll
    for (int i = 0; i < 4; ++i)
        gload_lds16(&rgt[(size_t)(i * 4 + wv) * CIN + l * 4],
                    &smem[(i * 4 + wv) * CHUNK]);
    pfx[0][0] = *(const float4*)&xr0[0];
    pfx[0][1] = *(const float4*)&xr1[0];
    __syncthreads();   // vmcnt(0) drain publishes buf0

#pragma unroll 2
    for (int c = 0; c < NCHUNK; ++c) {
        const int cb = c & 1, nb = (c + 1) & 1;
        // issue next chunk at the TOP: full compute period in flight.
        if (c + 1 < NCHUNK) {
            const int ko = (c + 1) * CHUNK;
#pragma unroll
            for (int i = 0; i < 4; ++i)
                gload_lds16(&rgt[(size_t)(i * 4 + wv) * CIN + ko + l * 4],
                            &smem[nb * 4096 + (i * 4 + wv) * CHUNK]);
            pfx[nb][0] = *(const float4*)&xr0[ko];
            pfx[nb][1] = *(const float4*)&xr1[ko];
        }
        // compute chunk c: 16 contiguous b128 reads + 128 fmac
        const float* rsb = &smem[cb * 4096];
        const float4 xv0 = pfx[cb][0], xv1 = pfx[cb][1];
#pragma unroll
        for (int r = 0; r < RK; ++r) {
            const float4 rv = *(const float4*)&rsb[r * CHUNK + l * 4];
            acc[0][r] += rv.x * xv0.x; acc[0][r] += rv.y * xv0.y;
            acc[0][r] += rv.z * xv0.z; acc[0][r] += rv.w * xv0.w;
            acc[1][r] += rv.x * xv1.x; acc[1][r] += rv.y * xv1.y;
            acc[1][r] += rv.z * xv1.z; acc[1][r] += rv.w * xv1.w;
        }
        if (c + 1 < NCHUNK) __syncthreads();   // publishes buf nb for iter c+1
    }

    // ---- k-reduce: 64 lanes -> 16 partials -> t[8][16]
#pragma unroll
    for (int rr = 0; rr < 2; ++rr)
#pragma unroll
        for (int r = 0; r < RK; ++r) {
            acc[rr][r] += __shfl_xor(acc[rr][r], 32);
            acc[rr][r] += __shfl_xor(acc[rr][r], 16);
        }
    // red aliases smem[0..2303]: buf0 reads ended at c=14 (fenced by that
    // barrier); c=15 read buf1 only; no loads pending into buf0.
    __syncthreads();
    if (l < 16) {
#pragma unroll
        for (int rr = 0; rr < 2; ++rr)
#pragma unroll
            for (int q = 0; q < 4; ++q)
                *(float4*)&smem[(wv * 16 + l) * RST + rr * 16 + q * 4] =
                    make_float4(acc[rr][q * 4 + 0], acc[rr][q * 4 + 1],
                                acc[rr][q * 4 + 2], acc[rr][q * 4 + 3]);
    }
    __syncthreads();
    if (tid < ROWS * RK) {
        const int row = tid >> 4, r = tid & 15;
        const int ws = row >> 1, rr = row & 1;
        float s = 0.f;
#pragma unroll
        for (int lp = 0; lp < 16; ++lp)
            s += smem[(ws * 16 + lp) * RST + rr * 16 + r];
        tl[row * RK + r] = s;
    }
    __syncthreads();

    // ---- phase 2: out[8][4096] = t @ left^T + bias.
    // 4 column chunks x 2 half-passes; lf{0,1}[4] = 32 regs peak.
#pragma unroll 1
    for (int oc = 0; oc < 4; ++oc) {
#pragma unroll 1
        for (int h = 0; h < 2; ++h) {
            const int o0 = oc * 1024 + h * 512 + tid * 2;
            float4 lf0[4], lf1[4];
#pragma unroll
            for (int q = 0; q < 4; ++q) {
                lf0[q] = *(const float4*)&lft[(size_t)o0 * RK + q * 4];
                lf1[q] = *(const float4*)&lft[(size_t)(o0 + 1) * RK + q * 4];
            }
            const float2 bv = *(const float2*)&bias[o0];

#pragma unroll
            for (int rr = 0; rr < ROWS; ++rr) {
                float4 ts[4];
#pragma unroll
                for (int q = 0; q < 4; ++q)
                    ts[q] = ((const float4*)tl)[rr * 4 + q];   // uniform -> broadcast

                float r0 = bv.x, r1 = bv.y;
#pragma unroll
                for (int q = 0; q < 4; ++q) {
                    r0 += lf0[q].x * ts[q].x; r0 += lf0[q].y * ts[q].y;
                    r0 += lf0[q].z * ts[q].z; r0 += lf0[q].w * ts[q].w;
                    r1 += lf1[q].x * ts[q].x; r1 += lf1[q].y * ts[q].y;
                    r1 += lf1[q].z * ts[q].z; r1 += lf1[q].w * ts[q].w;
                }
                *(float2*)&out[(size_t)(row0 + rr) * COUT + o0] =
                    make_float2(r0, r1);
            }
        }
    }
}

extern "C" void kernel_launch(void* const* d_in, const int* in_sizes, int n_in,
                              void* d_out, int out_size, void* d_ws, size_t ws_size,
                              hipStream_t stream)
{
    const float* x    = (const float*)d_in[0];
    const float* lft  = (const float*)d_in[1];   // [COUT][RK]
    const float* rgt  = (const float*)d_in[2];   // [RK][CIN]
    const float* bias = (const float*)d_in[3];
    float*       out  = (float*)d_out;

    (void)d_ws; (void)ws_size;                   // workspace unused

    fused<<<dim3(NT / ROWS), dim3(256), 0, stream>>>(x, rgt, lft, bias, out);
}